// Round 10
// baseline (162.276 us; speedup 1.0000x reference)
//
#include <hip/hip_runtime.h>

typedef __attribute__((ext_vector_type(4))) float f32x4;
typedef __attribute__((ext_vector_type(4))) int   i32x4;
typedef __attribute__((ext_vector_type(8))) int   i32x8;

#define DIM 256
#define D4  64    // float4 per row

// sqrt(log2(e)/2): rows normalized to THIS norm so MFMA output is directly the
// exp2 argument (verified exact in R9: absmax 0.0).
#define KSQRTC 0.84932216f

// async global->LDS, 16B per lane; LDS dest = wave-uniform base + lane*16.
#define GLD_LDS16(g, l) __builtin_amdgcn_global_load_lds(                      \
    (const __attribute__((address_space(1))) void*)(g),                        \
    (__attribute__((address_space(3))) void*)(l), 16, 0, 0)

// One wave per row. Rows [0,N): exact fp32 pos_sim -> posPart[row] + scaled-
// normalized pk -> fp8 e4m3 (plain byte-k order). Rows [N,N+M): nv likewise.
__global__ __launch_bounds__(256) void normalize_kernel(
    const float4* __restrict__ pk, const float4* __restrict__ pv,
    const float4* __restrict__ nv, unsigned int* __restrict__ pkn,
    unsigned int* __restrict__ nvn, float* __restrict__ posPart, int N) {
  int row  = blockIdx.x * 4 + (threadIdx.x >> 6);
  int lane = threadIdx.x & 63;
  if (row < N) {
    float4 x = pk[row * D4 + lane];
    float4 y = pv[row * D4 + lane];
    float skk = x.x*x.x + x.y*x.y + x.z*x.z + x.w*x.w;
    float svv = y.x*y.x + y.y*y.y + y.z*y.z + y.w*y.w;
    float skv = x.x*y.x + x.y*y.y + x.z*y.z + x.w*y.w;
#pragma unroll
    for (int m = 32; m >= 1; m >>= 1) {
      skk += __shfl_xor(skk, m, 64);
      svv += __shfl_xor(svv, m, 64);
      skv += __shfl_xor(skv, m, 64);
    }
    float nk  = fmaxf(sqrtf(skk), 1e-8f);
    float nvv = fmaxf(sqrtf(svv), 1e-8f);
    if (lane == 0) posPart[row] = skv / (nk * nvv);
    float rk = KSQRTC / nk;
    int w = __builtin_amdgcn_cvt_pk_fp8_f32(x.x * rk, x.y * rk, 0, false);
    w = __builtin_amdgcn_cvt_pk_fp8_f32(x.z * rk, x.w * rk, w, true);
    pkn[(size_t)row * 64 + lane] = (unsigned int)w;
  } else {
    int r2 = row - N;
    float4 x = nv[r2 * D4 + lane];
    float s = x.x*x.x + x.y*x.y + x.z*x.z + x.w*x.w;
#pragma unroll
    for (int m = 32; m >= 1; m >>= 1) s += __shfl_xor(s, m, 64);
    float rn = KSQRTC / fmaxf(sqrtf(s), 1e-8f);
    int w = __builtin_amdgcn_cvt_pk_fp8_f32(x.x * rn, x.y * rn, 0, false);
    w = __builtin_amdgcn_cvt_pk_fp8_f32(x.z * rn, x.w * rn, w, true);
    nvn[(size_t)r2 * 64 + lane] = (unsigned int)w;
  }
}

// Fused fp8 GEMM (MX 16x16x128, unit scales = exact fp8) + exp2(acc) + row-sum.
// R10 = R8's prefetch-across-barrier schedule, FIXED:
//  - R8 selected the LDS buffer at RUNTIME (Bs[(ct+1)&1]); LLVM's waitcnt pass
//    can't tell which buffer an outstanding global_load_lds targets, so it
//    emitted vmcnt(0) before every tile's frag reads — exposing the full
//    staging latency every tile (why R5..R8 all sat at 37-42us). Now Bs0/Bs1
//    are SEPARATE __shared__ arrays and the tile loop is unrolled in pairs:
//    each compute reads a buffer staged before the PREVIOUS barrier (whose
//    implicit vmcnt(0) proves completion) -> frag ds_reads need no vmcnt wait,
//    and each barrier drains a stage issued ~1700cyc earlier (complete, free).
//  - R9's register rp accumulation: ONE butterfly + store per wave per kernel.
//  - R9's spill lesson: no register ping-pong; B via LDS; VGPRs ~160 < 256.
// WG 256 thr = 4 waves (2x2 of 64x64), tile 128x128, 8 col tiles/WG,
// grid (8 colgroups, 64 stripes) = 512 WGs = 2/CU (LDS 64KB).
__global__ __launch_bounds__(256, 2) void gemm_lse_kernel(
    const unsigned char* __restrict__ gA, const unsigned char* __restrict__ gB,
    float* __restrict__ partial, int N) {
  __shared__ unsigned char Bs0[32768];   // [128 rows][16 chunks16B, XOR-swizzled]
  __shared__ unsigned char Bs1[32768];

  const int tid  = threadIdx.x;
  const int lane = tid & 63;
  const int wv   = tid >> 6;
  const int wm   = wv >> 1, wn = wv & 1;
  const int l15  = lane & 15, q = lane >> 4;
  const int row0 = blockIdx.y * 128;
  const int ct0  = blockIdx.x * 8;         // first col tile of this WG
  const int kUnitScale = 0x7F7F7F7F;       // e8m0 127 = 2^0 per byte

  // ---- A frags: persistent in VGPRs (R7/R8-verified byte order) ----
  const unsigned char* pa = gA + (size_t)(row0 + wm * 64 + l15) * 256 + q * 32;
  i32x4 alo[2][4], ahi[2][4];
#pragma unroll
  for (int kb = 0; kb < 2; kb++)
#pragma unroll
    for (int mi = 0; mi < 4; mi++) {
      alo[kb][mi] = *(const i32x4*)(pa + mi * 4096 + kb * 128);
      ahi[kb][mi] = *(const i32x4*)(pa + mi * 4096 + kb * 128 + 16);
    }

  // staging helper indices (thread -> 8 chunks of 16B, XOR-16 source swizzle)
  // lane-contiguous per wave; 16 consecutive lanes cover one 256B row.
#define STAGE_B(dst, tile)                                                     \
  {                                                                            \
    const unsigned char* pb = gB + (size_t)((tile) * 128) * 256;               \
    _Pragma("unroll")                                                          \
    for (int i = 0; i < 8; i++) {                                              \
      int c  = i * 256 + tid;                                                  \
      int r  = c >> 4;                                                         \
      int sc = ((c & 15) ^ (r & 15)) << 4;                                     \
      GLD_LDS16(pb + (size_t)r * 256 + sc, (dst) + c * 16);                    \
    }                                                                          \
  }

  float rp[4][4];
#pragma unroll
  for (int a = 0; a < 4; a++)
#pragma unroll
    for (int b = 0; b < 4; b++) rp[a][b] = 0.f;

  // compute one 128x128 tile from a statically-known buffer
#define COMPUTE_TILE(bs)                                                       \
  {                                                                            \
    f32x4 acc[4][4];                                                           \
    _Pragma("unroll")                                                          \
    for (int mi = 0; mi < 4; mi++)                                             \
      _Pragma("unroll")                                                        \
      for (int ni = 0; ni < 4; ni++) acc[mi][ni] = (f32x4){0.f, 0.f, 0.f, 0.f};\
    _Pragma("unroll")                                                          \
    for (int kb = 0; kb < 2; kb++) {                                           \
      i32x8 bf[4];                                                             \
      _Pragma("unroll")                                                        \
      for (int ni = 0; ni < 4; ni++) {                                         \
        int r  = wn * 64 + ni * 16 + l15;                                      \
        int c0 = (kb * 8 + q * 2)     ^ (r & 15);                              \
        int c1 = (kb * 8 + q * 2 + 1) ^ (r & 15);                              \
        i32x4 lo = *(const i32x4*)((bs) + r * 256 + c0 * 16);                  \
        i32x4 hi = *(const i32x4*)((bs) + r * 256 + c1 * 16);                  \
        bf[ni] = (i32x8){lo.x, lo.y, lo.z, lo.w, hi.x, hi.y, hi.z, hi.w};      \
      }                                                                        \
      _Pragma("unroll")                                                        \
      for (int mi = 0; mi < 4; mi++) {                                         \
        i32x8 af = (i32x8){alo[kb][mi].x, alo[kb][mi].y, alo[kb][mi].z,        \
                           alo[kb][mi].w, ahi[kb][mi].x, ahi[kb][mi].y,        \
                           ahi[kb][mi].z, ahi[kb][mi].w};                      \
        _Pragma("unroll")                                                      \
        for (int ni = 0; ni < 4; ni++)                                         \
          acc[mi][ni] = __builtin_amdgcn_mfma_scale_f32_16x16x128_f8f6f4(      \
              af, bf[ni], acc[mi][ni], 0, 0, 0, kUnitScale, 0, kUnitScale);    \
      }                                                                        \
    }                                                                          \
    _Pragma("unroll")                                                          \
    for (int mi = 0; mi < 4; mi++)                                             \
      _Pragma("unroll")                                                        \
      for (int ni = 0; ni < 4; ni++)                                           \
        _Pragma("unroll")                                                      \
        for (int rr = 0; rr < 4; rr++)                                         \
          rp[mi][rr] += __builtin_amdgcn_exp2f(acc[mi][ni][rr]);               \
  }

  STAGE_B(Bs0, ct0);
  __syncthreads();                       // drains Bs0 stage (vmcnt(0))

#pragma unroll
  for (int tp = 0; tp < 4; tp++) {
    // even tile 2tp from Bs0; prefetch odd tile into Bs1 first
    STAGE_B(Bs1, ct0 + 2 * tp + 1);
    COMPUTE_TILE(Bs0);
    __syncthreads();                     // drains Bs1 stage (~1700cyc old, free)
    // odd tile 2tp+1 from Bs1; prefetch next even tile into Bs0
    if (tp < 3) STAGE_B(Bs0, ct0 + 2 * tp + 2);
    COMPUTE_TILE(Bs1);
    if (tp < 3) __syncthreads();         // drains Bs0 stage; allows Bs1 reuse
  }

  // ---- single butterfly + one dense coalesced 256B store per wave ----
  // C/D layout (verified R2-R9): col = lane&15, row = quad*4 + rr.
  float keep = 0.f;
#pragma unroll
  for (int mi = 0; mi < 4; mi++)
#pragma unroll
    for (int rr = 0; rr < 4; rr++) {
      float v = rp[mi][rr];
      v += __shfl_xor(v, 1, 16);
      v += __shfl_xor(v, 2, 16);
      v += __shfl_xor(v, 4, 16);
      v += __shfl_xor(v, 8, 16);
      if (l15 == mi * 4 + rr) keep = v;
    }
  int lrow = (l15 >> 2) * 16 + q * 4 + (l15 & 3);
  partial[(size_t)(blockIdx.x * 2 + wn) * N + row0 + wm * 64 + lrow] = keep;
#undef STAGE_B
#undef COMPUTE_TILE
}

// out = mean(ln(sum_j partial[j][row])) - 0.5*mean(posPart). 16 slabs.
__global__ __launch_bounds__(256) void finalize_kernel(
    const float* __restrict__ partial, const float* __restrict__ posPart,
    float* __restrict__ out, int N, int slabsPerGroup, float invN) {
  __shared__ float red[4][64];
  int t  = threadIdx.x;
  int rl = t & 63, g = t >> 6;
  int row = blockIdx.x * 64 + rl;
  const float* p = partial + (size_t)(g * slabsPerGroup) * N + row;
  float s = 0.f;
#pragma unroll 4
  for (int j = 0; j < slabsPerGroup; j++) s += p[(size_t)j * N];
  red[g][rl] = s;
  __syncthreads();
  if (t < 64) {
    float tot = red[0][rl] + red[1][rl] + red[2][rl] + red[3][rl];
    float v = __builtin_amdgcn_logf(tot) * 0.69314718055994531f
              - 0.5f * posPart[row];
#pragma unroll
    for (int m = 32; m >= 1; m >>= 1) v += __shfl_xor(v, m, 64);
    if (rl == 0) atomicAdd(out, v * invN);
  }
}

extern "C" void kernel_launch(void* const* d_in, const int* in_sizes, int n_in,
                              void* d_out, int out_size, void* d_ws, size_t ws_size,
                              hipStream_t stream) {
  const float* pk = (const float*)d_in[0];
  const float* pv = (const float*)d_in[1];
  const float* nv = (const float*)d_in[2];
  int N = in_sizes[0] / DIM;   // 8192
  int M = in_sizes[2] / DIM;   // 8192
  float* out = (float*)d_out;

  unsigned char* pkn = (unsigned char*)d_ws;                   // [N,256] fp8
  unsigned char* nvn = pkn + (size_t)N * DIM;                  // [M,256] fp8
  float* partial = (float*)(nvn + (size_t)M * DIM);            // [16][N] fp32
  float* posPart = partial + (size_t)16 * N;                   // [N] fp32

  hipMemsetAsync(out, 0, sizeof(float), stream);

  normalize_kernel<<<(N + M) / 4, 256, 0, stream>>>(
      (const float4*)pk, (const float4*)pv, (const float4*)nv,
      (unsigned int*)pkn, (unsigned int*)nvn, posPart, N);

  gemm_lse_kernel<<<dim3(M / (128 * 8), N / 128), 256, 0, stream>>>(
      pkn, nvn, partial, N);

  finalize_kernel<<<N / 64, 256, 0, stream>>>(
      partial, posPart, out, N, 4, 1.0f / (float)N);
}

// Round 11
// 110.035 us; speedup vs baseline: 1.4748x; 1.4748x over previous
//
#include <hip/hip_runtime.h>

typedef __attribute__((ext_vector_type(4))) float f32x4;
typedef __attribute__((ext_vector_type(4))) int   i32x4;
typedef __attribute__((ext_vector_type(8))) int   i32x8;

#define DIM 256
#define D4  64    // float4 per row

// sqrt(log2(e)/2): rows normalized to THIS norm so MFMA output is directly the
// exp2 argument (verified exact R9/R10: absmax 0.0).
#define KSQRTC 0.84932216f

// async global->LDS, 16B per lane; LDS dest = wave-uniform base + lane*16.
#define GLD_LDS16(g, l) __builtin_amdgcn_global_load_lds(                      \
    (const __attribute__((address_space(1))) void*)(g),                        \
    (__attribute__((address_space(3))) void*)(l), 16, 0, 0)

// One wave per row. Rows [0,N): exact fp32 pos_sim -> posPart[row] + scaled-
// normalized pk -> fp8 e4m3 (plain byte-k order). Rows [N,N+M): nv likewise.
__global__ __launch_bounds__(256) void normalize_kernel(
    const float4* __restrict__ pk, const float4* __restrict__ pv,
    const float4* __restrict__ nv, unsigned int* __restrict__ pkn,
    unsigned int* __restrict__ nvn, float* __restrict__ posPart, int N) {
  int row  = blockIdx.x * 4 + (threadIdx.x >> 6);
  int lane = threadIdx.x & 63;
  if (row < N) {
    float4 x = pk[row * D4 + lane];
    float4 y = pv[row * D4 + lane];
    float skk = x.x*x.x + x.y*x.y + x.z*x.z + x.w*x.w;
    float svv = y.x*y.x + y.y*y.y + y.z*y.z + y.w*y.w;
    float skv = x.x*y.x + x.y*y.y + x.z*y.z + x.w*y.w;
#pragma unroll
    for (int m = 32; m >= 1; m >>= 1) {
      skk += __shfl_xor(skk, m, 64);
      svv += __shfl_xor(svv, m, 64);
      skv += __shfl_xor(skv, m, 64);
    }
    float nk  = fmaxf(sqrtf(skk), 1e-8f);
    float nvv = fmaxf(sqrtf(svv), 1e-8f);
    if (lane == 0) posPart[row] = skv / (nk * nvv);
    float rk = KSQRTC / nk;
    int w = __builtin_amdgcn_cvt_pk_fp8_f32(x.x * rk, x.y * rk, 0, false);
    w = __builtin_amdgcn_cvt_pk_fp8_f32(x.z * rk, x.w * rk, w, true);
    pkn[(size_t)row * 64 + lane] = (unsigned int)w;
  } else {
    int r2 = row - N;
    float4 x = nv[r2 * D4 + lane];
    float s = x.x*x.x + x.y*x.y + x.z*x.z + x.w*x.w;
#pragma unroll
    for (int m = 32; m >= 1; m >>= 1) s += __shfl_xor(s, m, 64);
    float rn = KSQRTC / fmaxf(sqrtf(s), 1e-8f);
    int w = __builtin_amdgcn_cvt_pk_fp8_f32(x.x * rn, x.y * rn, 0, false);
    w = __builtin_amdgcn_cvt_pk_fp8_f32(x.z * rn, x.w * rn, w, true);
    nvn[(size_t)r2 * 64 + lane] = (unsigned int)w;
  }
}

// Fused fp8 GEMM (MX 16x16x128, unit scales = exact fp8) + exp2(acc) + row-sum.
// R11: ONE-SHOT MEGA-STAGE. Evidence: every barrier-staged variant (R3..R8)
// plateaus at 34-55us because each CU runs 16 small stage->drain->compute
// phases with no cross-phase overlap; register-pipelining attempts (R9/R10)
// spill. So: make the phases 4x longer. WG = 4 waves owns 128 rows x 4 col
// tiles; stages ALL four B tiles (128KB dynamic LDS) with one drain, then runs
// 128 MFMAs + epilogue with ZERO further barriers (waves free-run; epilogue
// VALU of one wave hides under another's MFMA, m114). A frags live in VGPRs
// (R8-verified). Spill-proofing: launch_bounds(256,1) = 512-reg budget;
// tile loop NOT unrolled so the live set stays one tile wide (R9/R10 lesson).
// Grid (16,64) = 1024 WGs = 4/CU work, 1 resident (LDS-bound) - intended.
extern __shared__ unsigned char smem[];   // 131072 B = 4 x 32KB B tiles

__global__ __launch_bounds__(256, 1) void gemm_lse_kernel(
    const unsigned char* __restrict__ gA, const unsigned char* __restrict__ gB,
    float* __restrict__ partial, int N) {
  const int tid  = threadIdx.x;
  const int lane = tid & 63;
  const int wv   = tid >> 6;
  const int wm   = wv >> 1, wn = wv & 1;
  const int l15  = lane & 15, q = lane >> 4;
  const int row0 = blockIdx.y * 128;
  const int ct0  = blockIdx.x * 4;         // first of 4 col tiles
  const int kUnitScale = 0x7F7F7F7F;       // e8m0 127 = 2^0 per byte

  // ---- stage B for all 4 tiles: 8192 chunks of 16B, 32 per thread ----
  // XOR-16 source-side swizzle per 256B row (R4-verified conflict-free).
#pragma unroll
  for (int i = 0; i < 32; i++) {
    int c  = i * 256 + tid;                // 0..8191
    int tt = c >> 11;                      // tile 0..3
    int c2 = c & 2047;
    int r  = c2 >> 4;                      // row in tile 0..127
    int sc = ((c2 & 15) ^ (r & 15)) << 4;
    GLD_LDS16(gB + (size_t)((ct0 + tt) * 128 + r) * 256 + sc, smem + c * 16);
  }

  // ---- A frags: persistent in VGPRs (R7/R8-verified byte order) ----
  const unsigned char* pa = gA + (size_t)(row0 + wm * 64 + l15) * 256 + q * 32;
  i32x4 alo[2][4], ahi[2][4];
#pragma unroll
  for (int kb = 0; kb < 2; kb++)
#pragma unroll
    for (int mi = 0; mi < 4; mi++) {
      alo[kb][mi] = *(const i32x4*)(pa + mi * 4096 + kb * 128);
      ahi[kb][mi] = *(const i32x4*)(pa + mi * 4096 + kb * 128 + 16);
    }

  __syncthreads();                         // the ONLY barrier (drains staging)

  float rp[4][4];
#pragma unroll
  for (int a = 0; a < 4; a++)
#pragma unroll
    for (int b = 0; b < 4; b++) rp[a][b] = 0.f;

#pragma unroll 1                           // keep live set one tile wide
  for (int tt = 0; tt < 4; tt++) {
    const unsigned char* bs = smem + tt * 32768;
    f32x4 acc[4][4];
#pragma unroll
    for (int mi = 0; mi < 4; mi++)
#pragma unroll
      for (int ni = 0; ni < 4; ni++) acc[mi][ni] = (f32x4){0.f, 0.f, 0.f, 0.f};

#pragma unroll
    for (int kb = 0; kb < 2; kb++) {
      i32x8 bf[4];
#pragma unroll
      for (int ni = 0; ni < 4; ni++) {
        int r  = wn * 64 + ni * 16 + l15;
        int c0 = (kb * 8 + q * 2)     ^ (r & 15);
        int c1 = (kb * 8 + q * 2 + 1) ^ (r & 15);
        i32x4 lo = *(const i32x4*)(bs + r * 256 + c0 * 16);
        i32x4 hi = *(const i32x4*)(bs + r * 256 + c1 * 16);
        bf[ni] = (i32x8){lo.x, lo.y, lo.z, lo.w, hi.x, hi.y, hi.z, hi.w};
      }
#pragma unroll
      for (int mi = 0; mi < 4; mi++) {
        i32x8 af = (i32x8){alo[kb][mi].x, alo[kb][mi].y, alo[kb][mi].z,
                           alo[kb][mi].w, ahi[kb][mi].x, ahi[kb][mi].y,
                           ahi[kb][mi].z, ahi[kb][mi].w};
#pragma unroll
        for (int ni = 0; ni < 4; ni++)
          acc[mi][ni] = __builtin_amdgcn_mfma_scale_f32_16x16x128_f8f6f4(
              af, bf[ni], acc[mi][ni],
              0, 0,                        // cbsz/blgp = fp8 e4m3
              0, kUnitScale, 0, kUnitScale);
      }
    }
    // per-tile epilogue: exp2 (scale pre-folded into norms) into rp
#pragma unroll
    for (int mi = 0; mi < 4; mi++)
#pragma unroll
      for (int ni = 0; ni < 4; ni++)
#pragma unroll
        for (int rr = 0; rr < 4; rr++)
          rp[mi][rr] += __builtin_amdgcn_exp2f(acc[mi][ni][rr]);
  }

  // ---- single butterfly + one dense coalesced 256B store per wave ----
  // C/D layout (verified R2-R10): col = lane&15, row = quad*4 + rr.
  float keep = 0.f;
#pragma unroll
  for (int mi = 0; mi < 4; mi++)
#pragma unroll
    for (int rr = 0; rr < 4; rr++) {
      float v = rp[mi][rr];
      v += __shfl_xor(v, 1, 16);
      v += __shfl_xor(v, 2, 16);
      v += __shfl_xor(v, 4, 16);
      v += __shfl_xor(v, 8, 16);
      if (l15 == mi * 4 + rr) keep = v;
    }
  int lrow = (l15 >> 2) * 16 + q * 4 + (l15 & 3);
  partial[(size_t)(blockIdx.x * 2 + wn) * N + row0 + wm * 64 + lrow] = keep;
}

// out = mean(ln(sum_j partial[j][row])) - 0.5*mean(posPart). 32 slabs.
__global__ __launch_bounds__(256) void finalize_kernel(
    const float* __restrict__ partial, const float* __restrict__ posPart,
    float* __restrict__ out, int N, int slabsPerGroup, float invN) {
  __shared__ float red[4][64];
  int t  = threadIdx.x;
  int rl = t & 63, g = t >> 6;
  int row = blockIdx.x * 64 + rl;
  const float* p = partial + (size_t)(g * slabsPerGroup) * N + row;
  float s = 0.f;
#pragma unroll 8
  for (int j = 0; j < slabsPerGroup; j++) s += p[(size_t)j * N];
  red[g][rl] = s;
  __syncthreads();
  if (t < 64) {
    float tot = red[0][rl] + red[1][rl] + red[2][rl] + red[3][rl];
    float v = __builtin_amdgcn_logf(tot) * 0.69314718055994531f
              - 0.5f * posPart[row];
#pragma unroll
    for (int m = 32; m >= 1; m >>= 1) v += __shfl_xor(v, m, 64);
    if (rl == 0) atomicAdd(out, v * invN);
  }
}

extern "C" void kernel_launch(void* const* d_in, const int* in_sizes, int n_in,
                              void* d_out, int out_size, void* d_ws, size_t ws_size,
                              hipStream_t stream) {
  const float* pk = (const float*)d_in[0];
  const float* pv = (const float*)d_in[1];
  const float* nv = (const float*)d_in[2];
  int N = in_sizes[0] / DIM;   // 8192
  int M = in_sizes[2] / DIM;   // 8192
  float* out = (float*)d_out;

  unsigned char* pkn = (unsigned char*)d_ws;                   // [N,256] fp8
  unsigned char* nvn = pkn + (size_t)N * DIM;                  // [M,256] fp8
  float* partial = (float*)(nvn + (size_t)M * DIM);            // [32][N] fp32
  float* posPart = partial + (size_t)32 * N;                   // [N] fp32

  // allow 128KB dynamic LDS (host-side attribute; graph-capture safe)
  hipFuncSetAttribute((const void*)gemm_lse_kernel,
                      hipFuncAttributeMaxDynamicSharedMemorySize, 131072);

  hipMemsetAsync(out, 0, sizeof(float), stream);

  normalize_kernel<<<(N + M) / 4, 256, 0, stream>>>(
      (const float4*)pk, (const float4*)pv, (const float4*)nv,
      (unsigned int*)pkn, (unsigned int*)nvn, posPart, N);

  gemm_lse_kernel<<<dim3(M / 512, N / 128), 256, 131072, stream>>>(
      pkn, nvn, partial, N);

  finalize_kernel<<<N / 64, 256, 0, stream>>>(
      partial, posPart, out, N, 8, 1.0f / (float)N);
}